// Round 15
// baseline (142.771 us; speedup 1.0000x reference)
//
#include <hip/hip_runtime.h>
#include <cstdint>

typedef __attribute__((ext_vector_type(8))) short short8;
typedef __attribute__((ext_vector_type(4))) float f32x4;
typedef __attribute__((ext_vector_type(2))) float f32x2;
typedef __attribute__((ext_vector_type(4))) unsigned uint32x4;

#define NE 128     // n_e (K)
#define RR 256     // RANK*RANK (N)
#define MT 64      // batch rows per block
#define JST 260    // jbuf per-matrix stride (words)

__device__ __forceinline__ float u2f(unsigned u) { return __builtin_bit_cast(float, u); }
__device__ __forceinline__ unsigned f2u(float f) { return __builtin_bit_cast(unsigned, f); }
__device__ __forceinline__ unsigned short f2bf(float x) {
  unsigned u = f2u(x);
  unsigned r = (u + 0x7FFFu + ((u >> 16) & 1u)) >> 16;
  return (unsigned short)r;
}
__device__ __forceinline__ float bf2f(unsigned short h) {
  return u2f(((unsigned)h) << 16);
}
__device__ __forceinline__ float bperm_f(int byteidx, float v) {
  return __builtin_bit_cast(float,
      __builtin_amdgcn_ds_bpermute(byteidx, __builtin_bit_cast(int, v)));
}
// HW packed f32->bf16 RNE convert (gfx950)
__device__ __forceinline__ unsigned cvt_pk_bf16(float lo, float hi) {
  unsigned r;
  asm("v_cvt_pk_bf16_f32 %0, %1, %2" : "=v"(r) : "v"(lo), "v"(hi));
  return r;
}

// scalar 3-way RNE split (pre-kernel only)
__device__ __forceinline__ void split3(float x, unsigned short& a,
                                       unsigned short& b, unsigned short& c) {
  unsigned short h1 = f2bf(x);
  float r1 = x - bf2f(h1);
  unsigned short h2 = f2bf(r1);
  float r2 = r1 - bf2f(h2);
  a = h1; b = h2; c = f2bf(r2);
}

// ---- pre-kernel: 3-way split W (f32 [128][256]) -> h/m/l bf16, fragment-major
__global__ __launch_bounds__(256)
void wsplit3_kernel(const float* __restrict__ W,
                    unsigned short* __restrict__ wh,
                    unsigned short* __restrict__ wm,
                    unsigned short* __restrict__ wl) {
  int t = blockIdx.x * 256 + threadIdx.x;   // 0..32767
  int k = t >> 8, col = t & 255;
  unsigned short h1, h2, h3;
  split3(W[t], h1, h2, h3);
  int kt = k >> 5, klo = k & 31;
  int lane = ((klo >> 3) << 4) | (col & 15);
  int u = klo & 7;
  int ct = col >> 4;
  int e = ((kt * 16 + ct) * 64 + lane) * 8 + u;
  wh[e] = h1; wm[e] = h2; wl[e] = h3;
}

// ---- main fused kernel ----
// R14 base. Changes (both on the LU serial chain):
//  (a) payload-carrying DPP argmax -> pivot VALUE is lane-local, the 16
//      per-matrix pivot ds_bpermutes (~60cy each, on-chain) are gone
//  (b) raw v_rcp_f32 (no NR) — R13 proved LU insensitive to ulp-level rp error
// (256,2): R7/R9/R10 — tighter bounds make the allocator AGPR-shuffle the LU set.
__global__ __launch_bounds__(256, 2)
void jastrow_mfma(const float* __restrict__ occ,
                  const unsigned short* __restrict__ wh,
                  const unsigned short* __restrict__ wm,
                  const unsigned short* __restrict__ wl,
                  const float* __restrict__ bias,
                  float* __restrict__ out, int B) {
  // phase A: occS f32 [64][132] = 33792 B (aliased); phase B: jbuf f32 [64][260] = 66560 B
  __shared__ __align__(16) char smem[MT * JST * 4];
  float* occS = (float*)smem;
  float* jbuf = (float*)smem;

  const int tid  = threadIdx.x;
  const int lane = tid & 63;
  const int wv   = tid >> 6;        // wave 0..3
  const int wr   = wv >> 1;         // batch-row half (32 rows)
  const int wc   = wv & 1;          // W-col half (128 cols)
  const int l15  = lane & 15;
  const int lh   = lane >> 4;
  const long long b0 = (long long)blockIdx.x * MT;

  // ---- stage occ tile 64x128 f32 -> LDS [64][132] (coalesced) ----
  {
    const float* src = occ + b0 * NE;
    #pragma unroll
    for (int p = 0; p < 8; p++) {
      int flat = (tid + p * 256) * 4;
      int row = flat >> 7, e = flat & 127;
      f32x4 v = *(const f32x4*)(src + flat);
      *(f32x4*)(occS + row * 132 + e) = v;
    }
  }
  __syncthreads();

  // ---- occ fragments: 3-way bf16 split via v_cvt_pk_bf16_f32 ----
  short8 Ah[2][4], Am[2][4], Al[2][4];
  #pragma unroll
  for (int rt = 0; rt < 2; rt++) {
    #pragma unroll
    for (int kt = 0; kt < 4; kt++) {
      const float* p = occS + (wr * 32 + rt * 16 + l15) * 132 + kt * 32 + lh * 8;
      f32x4 v0 = *(const f32x4*)p;
      f32x4 v1 = *(const f32x4*)(p + 4);
      float xs[8] = {v0[0], v0[1], v0[2], v0[3], v1[0], v1[1], v1[2], v1[3]};
      uint32x4 ph, pm, pl;
      #pragma unroll
      for (int q = 0; q < 4; q++) {
        float x0 = xs[2*q], x1 = xs[2*q+1];
        unsigned h = cvt_pk_bf16(x0, x1);
        float r0 = x0 - u2f(h << 16);
        float r1 = x1 - u2f(h & 0xFFFF0000u);
        unsigned m = cvt_pk_bf16(r0, r1);
        float s0 = r0 - u2f(m << 16);
        float s1 = r1 - u2f(m & 0xFFFF0000u);
        unsigned l = cvt_pk_bf16(s0, s1);
        ph[q] = h; pm[q] = m; pl[q] = l;
      }
      Ah[rt][kt] = __builtin_bit_cast(short8, ph);
      Am[rt][kt] = __builtin_bit_cast(short8, pm);
      Al[rt][kt] = __builtin_bit_cast(short8, pl);
    }
  }
  __syncthreads();   // all occS reads done; jbuf may be written after this

  // ---- GEMM (swapped): acc[rt][ct] = j^T fragment; 6-MFMA triple-split ----
  f32x4 acc[2][8];
  #pragma unroll
  for (int ct = 0; ct < 8; ct++) {
    f32x4 bv = *(const f32x4*)(bias + (wc * 8 + ct) * 16 + lh * 4);
    acc[0][ct] = bv; acc[1][ct] = bv;
  }
  #pragma unroll
  for (int kt = 0; kt < 4; kt++) {
    #pragma unroll
    for (int ct = 0; ct < 8; ct++) {
      const int ctg = wc * 8 + ct;
      int fo = ((kt * 16 + ctg) * 64 + lane) * 8;
      short8 bh = *(const short8*)(wh + fo);
      short8 bm = *(const short8*)(wm + fo);
      short8 bl = *(const short8*)(wl + fo);
      #pragma unroll
      for (int rt = 0; rt < 2; rt++) {
        f32x4 c = acc[rt][ct];
        c = __builtin_amdgcn_mfma_f32_16x16x32_bf16(bh, Ah[rt][kt], c, 0, 0, 0);
        c = __builtin_amdgcn_mfma_f32_16x16x32_bf16(bm, Ah[rt][kt], c, 0, 0, 0);
        c = __builtin_amdgcn_mfma_f32_16x16x32_bf16(bh, Am[rt][kt], c, 0, 0, 0);
        c = __builtin_amdgcn_mfma_f32_16x16x32_bf16(bm, Am[rt][kt], c, 0, 0, 0);
        c = __builtin_amdgcn_mfma_f32_16x16x32_bf16(bl, Ah[rt][kt], c, 0, 0, 0);
        c = __builtin_amdgcn_mfma_f32_16x16x32_bf16(bh, Al[rt][kt], c, 0, 0, 0);
        acc[rt][ct] = c;
      }
    }
  }

  // ---- write j to jbuf: 16 x ds_write_b128 ----
  #pragma unroll
  for (int ct = 0; ct < 8; ct++) {
    const int ctg = wc * 8 + ct;
    #pragma unroll
    for (int rt = 0; rt < 2; rt++) {
      int m = wr * 32 + rt * 16 + l15;
      *(f32x4*)&jbuf[m * JST + ctg * 16 + lh * 4] = acc[rt][ct];
    }
  }
  __syncthreads();

  // ---- L=4 LU, 16 matrices per wave, all 4 waves active ----
  const int l4 = lane & 3;          // lane within matrix group
  const int g  = lane >> 2;         // group 0..15 in wave
  const int gm = wv * 16 + g;       // matrix 0..63
  #define XW(i, j) (xp[i][(j) >> 1][(j) & 1])

  f32x2 xp[4][8];                   // rows l4+4i, 8 column pairs
  #pragma unroll
  for (int i = 0; i < 4; i++) {
    #pragma unroll
    for (int c4 = 0; c4 < 4; c4++) {
      f32x4 v = *(const f32x4*)&jbuf[gm * JST + (l4 + 4 * i) * 16 + c4 * 4];
      f32x2 t0; t0[0] = v[0]; t0[1] = v[1];
      f32x2 t1; t1[0] = v[2]; t1[1] = v[3];
      xp[i][c4 * 2]     = t0;
      xp[i][c4 * 2 + 1] = t1;
    }
  }
  // A = I + j : diag col of row l4+4i is l4+4i
  #pragma unroll
  for (int i = 0; i < 4; i++) {
    xp[i][2*i][0]     += (l4 == 0) ? 1.0f : 0.0f;
    xp[i][2*i][1]     += (l4 == 1) ? 1.0f : 0.0f;
    xp[i][2*i + 1][0] += (l4 == 2) ? 1.0f : 0.0f;
    xp[i][2*i + 1][1] += (l4 == 3) ? 1.0f : 0.0f;
  }

  unsigned used = 0u;
  int par = 0;
  int esum = 0;
  float prodm = 1.0f;
  const int lbase = (lane & 60) << 2;   // quad base, byte index
  #pragma unroll
  for (int k = 0; k < 16; k++) {
    // packed argmax WITH PAYLOAD over 16 rows (4 local + 2 quad DPP stages)
    float xk[4];
    unsigned kmax = 0u;
    float vmax = 0.0f;
    #pragma unroll
    for (int i = 0; i < 4; i++) {
      xk[i] = XW(i, k);
      bool act = ((used >> (l4 + 4 * i)) & 1u) == 0u;
      unsigned ab = f2u(fabsf(xk[i]));
      unsigned code = (unsigned)(15 - 4 * i) - (unsigned)l4;
      unsigned key = act ? ((ab & 0xFFFFFFE0u) | 0x10u | code) : 0u;
      bool gt = key > kmax;
      kmax = gt ? key : kmax;
      vmax = gt ? xk[i] : vmax;
    }
    {
      unsigned ko = (unsigned)__builtin_amdgcn_update_dpp(0, (int)kmax, 0xB1, 0xF, 0xF, true);
      float    vo = u2f((unsigned)__builtin_amdgcn_update_dpp(0, (int)f2u(vmax), 0xB1, 0xF, 0xF, true));
      bool gt = ko > kmax; kmax = gt ? ko : kmax; vmax = gt ? vo : vmax;
    }
    {
      unsigned ko = (unsigned)__builtin_amdgcn_update_dpp(0, (int)kmax, 0x4E, 0xF, 0xF, true);
      float    vo = u2f((unsigned)__builtin_amdgcn_update_dpp(0, (int)f2u(vmax), 0x4E, 0xF, 0xF, true));
      bool gt = ko > kmax; kmax = gt ? ko : kmax; vmax = gt ? vo : vmax;
    }
    const int p = 15 - (int)(kmax & 0xFu);
    const bool pb0 = (p & 4) != 0;   // owner row-slot bit0
    const bool pb1 = (p & 8) != 0;   // owner row-slot bit1
    const int bidx = lbase | ((p & 3) << 2);
    const float piv = vmax;          // pivot value, no bpermute needed

    int e; float mant = frexpf(piv, &e);
    prodm *= mant; esum += e;
    par ^= __popc(used & (0xFFFFFFFFu << (p + 1))) & 1;  // inversion parity
    used |= 1u << p;

    // raw rcp (1 ulp) — R13 showed LU tolerates ulp-level rp error
    float rp = __builtin_amdgcn_rcpf(piv);
    rp = (piv != 0.0f) ? rp : 0.0f;

    f32x2 mf[4];
    #pragma unroll
    for (int i = 0; i < 4; i++) {
      bool act = ((used >> (l4 + 4 * i)) & 1u) == 0u;  // post-update mask (owner frozen)
      float f = act ? xk[i] * rp : 0.0f;
      mf[i][0] = -f; mf[i][1] = -f;
    }
    #pragma unroll
    for (int jp = (k + 1) >> 1; jp < 8; jp++) {
      float a01 = pb0 ? XW(1, 2 * jp) : XW(0, 2 * jp);
      float a23 = pb0 ? XW(3, 2 * jp) : XW(2, 2 * jp);
      float t0 = bperm_f(bidx, pb1 ? a23 : a01);
      float b01 = pb0 ? XW(1, 2 * jp + 1) : XW(0, 2 * jp + 1);
      float b23 = pb0 ? XW(3, 2 * jp + 1) : XW(2, 2 * jp + 1);
      float t1 = bperm_f(bidx, pb1 ? b23 : b01);
      f32x2 tp; tp[0] = t0; tp[1] = t1;
      #pragma unroll
      for (int i = 0; i < 4; i++)
        xp[i][jp] = __builtin_elementwise_fma(tp, mf[i], xp[i][jp]);
    }
  }
  if (l4 == 0) {
    float la = (__log2f(fabsf(prodm)) + (float)esum) * 0.6931471805599453f;
    int neg = (prodm < 0.0f) ? 1 : 0;
    float sg = (prodm == 0.0f) ? 0.0f : (((neg ^ par) != 0) ? -1.0f : 1.0f);
    long long b = b0 + gm;
    out[b] = sg;
    out[(long long)B + b] = la;
  }
  #undef XW
}

extern "C" void kernel_launch(void* const* d_in, const int* in_sizes, int n_in,
                              void* d_out, int out_size, void* d_ws, size_t ws_size,
                              hipStream_t stream) {
  const float* occ  = (const float*)d_in[0];
  const float* Wg   = (const float*)d_in[1];
  const float* bias = (const float*)d_in[2];
  float* out = (float*)d_out;
  const int B = in_sizes[0] / NE;          // 262144
  unsigned short* wh = (unsigned short*)d_ws;
  unsigned short* wm = wh + NE * RR;
  unsigned short* wl = wm + NE * RR;       // 196608 B total in d_ws

  hipLaunchKernelGGL(wsplit3_kernel, dim3(NE * RR / 256), dim3(256), 0, stream,
                     Wg, wh, wm, wl);
  hipLaunchKernelGGL(jastrow_mfma, dim3(B / MT), dim3(256), 0, stream,
                     occ, wh, wm, wl, bias, out, B);
}

// Round 17
// 138.690 us; speedup vs baseline: 1.0294x; 1.0294x over previous
//
#include <hip/hip_runtime.h>
#include <cstdint>

typedef __attribute__((ext_vector_type(8))) short short8;
typedef __attribute__((ext_vector_type(4))) float f32x4;
typedef __attribute__((ext_vector_type(2))) float f32x2;
typedef __attribute__((ext_vector_type(4))) unsigned uint32x4;

#define NE 128     // n_e (K)
#define RR 256     // RANK*RANK (N)
#define MT 64      // batch rows per block
#define JST 260    // jbuf per-matrix stride (words)

__device__ __forceinline__ float u2f(unsigned u) { return __builtin_bit_cast(float, u); }
__device__ __forceinline__ unsigned f2u(float f) { return __builtin_bit_cast(unsigned, f); }
__device__ __forceinline__ unsigned short f2bf(float x) {
  unsigned u = f2u(x);
  unsigned r = (u + 0x7FFFu + ((u >> 16) & 1u)) >> 16;
  return (unsigned short)r;
}
__device__ __forceinline__ float bf2f(unsigned short h) {
  return u2f(((unsigned)h) << 16);
}
__device__ __forceinline__ float bperm_f(int byteidx, float v) {
  return __builtin_bit_cast(float,
      __builtin_amdgcn_ds_bpermute(byteidx, __builtin_bit_cast(int, v)));
}
template<int CTRL>
__device__ __forceinline__ unsigned dpp_maxu(unsigned k) {
  unsigned o = (unsigned)__builtin_amdgcn_update_dpp(0, (int)k, CTRL, 0xF, 0xF, true);
  return o > k ? o : k;
}
// HW packed f32->bf16 RNE convert (gfx950)
__device__ __forceinline__ unsigned cvt_pk_bf16(float lo, float hi) {
  unsigned r;
  asm("v_cvt_pk_bf16_f32 %0, %1, %2" : "=v"(r) : "v"(lo), "v"(hi));
  return r;
}

// scalar 3-way RNE split (pre-kernel only)
__device__ __forceinline__ void split3(float x, unsigned short& a,
                                       unsigned short& b, unsigned short& c) {
  unsigned short h1 = f2bf(x);
  float r1 = x - bf2f(h1);
  unsigned short h2 = f2bf(r1);
  float r2 = r1 - bf2f(h2);
  a = h1; b = h2; c = f2bf(r2);
}

// ---- pre-kernel: 3-way split W (f32 [128][256]) -> h/m/l bf16, fragment-major
// (16x16x32 fragment geometry — R3..R14 proven)
__global__ __launch_bounds__(256)
void wsplit3_kernel(const float* __restrict__ W,
                    unsigned short* __restrict__ wh,
                    unsigned short* __restrict__ wm,
                    unsigned short* __restrict__ wl) {
  int t = blockIdx.x * 256 + threadIdx.x;   // 0..32767
  int k = t >> 8, col = t & 255;
  unsigned short h1, h2, h3;
  split3(W[t], h1, h2, h3);
  int kt = k >> 5, klo = k & 31;
  int lane = ((klo >> 3) << 4) | (col & 15);
  int u = klo & 7;
  int ct = col >> 4;
  int e = ((kt * 16 + ct) * 64 + lane) * 8 + u;
  wh[e] = h1; wm[e] = h2; wl[e] = h3;
}

// ---- main fused kernel ----
// R14 base (139.1us proven best). Only change: raw v_rcp_f32 (no Newton step)
// — R15 isolated raw-rcp numerics (same pivots as R14, absmax 0.125 < thr).
// R16's 32x32 MFMA attempt failed (sign=2.0): 32x32 A/B+C/D swap mapping has
// an unverified degree of freedom — branch closed, 16x16x32 retained.
// (256,2): R7/R9/R10 — tighter bounds make the allocator AGPR-shuffle the LU set.
__global__ __launch_bounds__(256, 2)
void jastrow_mfma(const float* __restrict__ occ,
                  const unsigned short* __restrict__ wh,
                  const unsigned short* __restrict__ wm,
                  const unsigned short* __restrict__ wl,
                  const float* __restrict__ bias,
                  float* __restrict__ out, int B) {
  // phase A: occS f32 [64][132] = 33792 B (aliased); phase B: jbuf f32 [64][260] = 66560 B
  __shared__ __align__(16) char smem[MT * JST * 4];
  float* occS = (float*)smem;
  float* jbuf = (float*)smem;

  const int tid  = threadIdx.x;
  const int lane = tid & 63;
  const int wv   = tid >> 6;        // wave 0..3
  const int wr   = wv >> 1;         // batch-row half (32 rows)
  const int wc   = wv & 1;          // W-col half (128 cols)
  const int l15  = lane & 15;
  const int lh   = lane >> 4;
  const long long b0 = (long long)blockIdx.x * MT;

  // ---- stage occ tile 64x128 f32 -> LDS [64][132] (coalesced; staging IS the
  // coalescer — R13 proved direct strided loads regress) ----
  {
    const float* src = occ + b0 * NE;
    #pragma unroll
    for (int p = 0; p < 8; p++) {
      int flat = (tid + p * 256) * 4;
      int row = flat >> 7, e = flat & 127;
      f32x4 v = *(const f32x4*)(src + flat);
      *(f32x4*)(occS + row * 132 + e) = v;
    }
  }
  __syncthreads();

  // ---- occ fragments: 3-way bf16 split via v_cvt_pk_bf16_f32 ----
  short8 Ah[2][4], Am[2][4], Al[2][4];
  #pragma unroll
  for (int rt = 0; rt < 2; rt++) {
    #pragma unroll
    for (int kt = 0; kt < 4; kt++) {
      const float* p = occS + (wr * 32 + rt * 16 + l15) * 132 + kt * 32 + lh * 8;
      f32x4 v0 = *(const f32x4*)p;
      f32x4 v1 = *(const f32x4*)(p + 4);
      float xs[8] = {v0[0], v0[1], v0[2], v0[3], v1[0], v1[1], v1[2], v1[3]};
      uint32x4 ph, pm, pl;
      #pragma unroll
      for (int q = 0; q < 4; q++) {
        float x0 = xs[2*q], x1 = xs[2*q+1];
        unsigned h = cvt_pk_bf16(x0, x1);
        float r0 = x0 - u2f(h << 16);
        float r1 = x1 - u2f(h & 0xFFFF0000u);
        unsigned m = cvt_pk_bf16(r0, r1);
        float s0 = r0 - u2f(m << 16);
        float s1 = r1 - u2f(m & 0xFFFF0000u);
        unsigned l = cvt_pk_bf16(s0, s1);
        ph[q] = h; pm[q] = m; pl[q] = l;
      }
      Ah[rt][kt] = __builtin_bit_cast(short8, ph);
      Am[rt][kt] = __builtin_bit_cast(short8, pm);
      Al[rt][kt] = __builtin_bit_cast(short8, pl);
    }
  }
  __syncthreads();   // all occS reads done; jbuf may be written after this

  // ---- GEMM (swapped): acc[rt][ct] = j^T fragment; 6-MFMA triple-split ----
  f32x4 acc[2][8];
  #pragma unroll
  for (int ct = 0; ct < 8; ct++) {
    f32x4 bv = *(const f32x4*)(bias + (wc * 8 + ct) * 16 + lh * 4);
    acc[0][ct] = bv; acc[1][ct] = bv;
  }
  #pragma unroll
  for (int kt = 0; kt < 4; kt++) {
    #pragma unroll
    for (int ct = 0; ct < 8; ct++) {
      const int ctg = wc * 8 + ct;
      int fo = ((kt * 16 + ctg) * 64 + lane) * 8;
      short8 bh = *(const short8*)(wh + fo);
      short8 bm = *(const short8*)(wm + fo);
      short8 bl = *(const short8*)(wl + fo);
      #pragma unroll
      for (int rt = 0; rt < 2; rt++) {
        f32x4 c = acc[rt][ct];
        c = __builtin_amdgcn_mfma_f32_16x16x32_bf16(bh, Ah[rt][kt], c, 0, 0, 0);
        c = __builtin_amdgcn_mfma_f32_16x16x32_bf16(bm, Ah[rt][kt], c, 0, 0, 0);
        c = __builtin_amdgcn_mfma_f32_16x16x32_bf16(bh, Am[rt][kt], c, 0, 0, 0);
        c = __builtin_amdgcn_mfma_f32_16x16x32_bf16(bm, Am[rt][kt], c, 0, 0, 0);
        c = __builtin_amdgcn_mfma_f32_16x16x32_bf16(bl, Ah[rt][kt], c, 0, 0, 0);
        c = __builtin_amdgcn_mfma_f32_16x16x32_bf16(bh, Al[rt][kt], c, 0, 0, 0);
        acc[rt][ct] = c;
      }
    }
  }

  // ---- write j to jbuf: 16 x ds_write_b128 ----
  #pragma unroll
  for (int ct = 0; ct < 8; ct++) {
    const int ctg = wc * 8 + ct;
    #pragma unroll
    for (int rt = 0; rt < 2; rt++) {
      int m = wr * 32 + rt * 16 + l15;
      *(f32x4*)&jbuf[m * JST + ctg * 16 + lh * 4] = acc[rt][ct];
    }
  }
  __syncthreads();

  // ---- L=4 LU, 16 matrices per wave, all 4 waves active ----
  const int l4 = lane & 3;          // lane within matrix group
  const int g  = lane >> 2;         // group 0..15 in wave
  const int gm = wv * 16 + g;       // matrix 0..63
  #define XW(i, j) (xp[i][(j) >> 1][(j) & 1])

  f32x2 xp[4][8];                   // rows l4+4i, 8 column pairs
  #pragma unroll
  for (int i = 0; i < 4; i++) {
    #pragma unroll
    for (int c4 = 0; c4 < 4; c4++) {
      f32x4 v = *(const f32x4*)&jbuf[gm * JST + (l4 + 4 * i) * 16 + c4 * 4];
      f32x2 t0; t0[0] = v[0]; t0[1] = v[1];
      f32x2 t1; t1[0] = v[2]; t1[1] = v[3];
      xp[i][c4 * 2]     = t0;
      xp[i][c4 * 2 + 1] = t1;
    }
  }
  // A = I + j : diag col of row l4+4i is l4+4i
  #pragma unroll
  for (int i = 0; i < 4; i++) {
    xp[i][2*i][0]     += (l4 == 0) ? 1.0f : 0.0f;
    xp[i][2*i][1]     += (l4 == 1) ? 1.0f : 0.0f;
    xp[i][2*i + 1][0] += (l4 == 2) ? 1.0f : 0.0f;
    xp[i][2*i + 1][1] += (l4 == 3) ? 1.0f : 0.0f;
  }

  unsigned used = 0u;
  int par = 0;
  int esum = 0;
  float prodm = 1.0f;
  const int lbase = (lane & 60) << 2;   // quad base, byte index
  #pragma unroll
  for (int k = 0; k < 16; k++) {
    // packed argmax over 16 rows (4 local + quad DPP reduce)
    float xk[4];
    unsigned kmax = 0u;
    #pragma unroll
    for (int i = 0; i < 4; i++) {
      xk[i] = XW(i, k);
      bool act = ((used >> (l4 + 4 * i)) & 1u) == 0u;
      unsigned ab = f2u(fabsf(xk[i]));
      unsigned code = (unsigned)(15 - 4 * i) - (unsigned)l4;
      unsigned key = act ? ((ab & 0xFFFFFFE0u) | 0x10u | code) : 0u;
      kmax = key > kmax ? key : kmax;
    }
    kmax = dpp_maxu<0xB1>(kmax);   // quad_perm [1,0,3,2]
    kmax = dpp_maxu<0x4E>(kmax);   // quad_perm [2,3,0,1]
    const int p = 15 - (int)(kmax & 0xFu);
    const bool pb0 = (p & 4) != 0;   // owner row-slot bit0
    const bool pb1 = (p & 8) != 0;   // owner row-slot bit1
    const int bidx = lbase | ((p & 3) << 2);

    float s01 = pb0 ? XW(1, k) : XW(0, k);
    float s23 = pb0 ? XW(3, k) : XW(2, k);
    float piv = bperm_f(bidx, pb1 ? s23 : s01);

    int e; float mant = frexpf(piv, &e);
    prodm *= mant; esum += e;
    par ^= __popc(used & (0xFFFFFFFFu << (p + 1))) & 1;  // inversion parity
    used |= 1u << p;

    // raw rcp (R15 isolated: same pivots as R14, absmax 0.125 — safe)
    float rp = __builtin_amdgcn_rcpf(piv);
    rp = (piv != 0.0f) ? rp : 0.0f;

    f32x2 mf[4];
    #pragma unroll
    for (int i = 0; i < 4; i++) {
      bool act = ((used >> (l4 + 4 * i)) & 1u) == 0u;  // post-update mask (owner frozen)
      float f = act ? xk[i] * rp : 0.0f;
      mf[i][0] = -f; mf[i][1] = -f;
    }
    #pragma unroll
    for (int jp = (k + 1) >> 1; jp < 8; jp++) {
      float a01 = pb0 ? XW(1, 2 * jp) : XW(0, 2 * jp);
      float a23 = pb0 ? XW(3, 2 * jp) : XW(2, 2 * jp);
      float t0 = bperm_f(bidx, pb1 ? a23 : a01);
      float b01 = pb0 ? XW(1, 2 * jp + 1) : XW(0, 2 * jp + 1);
      float b23 = pb0 ? XW(3, 2 * jp + 1) : XW(2, 2 * jp + 1);
      float t1 = bperm_f(bidx, pb1 ? b23 : b01);
      f32x2 tp; tp[0] = t0; tp[1] = t1;
      #pragma unroll
      for (int i = 0; i < 4; i++)
        xp[i][jp] = __builtin_elementwise_fma(tp, mf[i], xp[i][jp]);
    }
  }
  if (l4 == 0) {
    float la = (__log2f(fabsf(prodm)) + (float)esum) * 0.6931471805599453f;
    int neg = (prodm < 0.0f) ? 1 : 0;
    float sg = (prodm == 0.0f) ? 0.0f : (((neg ^ par) != 0) ? -1.0f : 1.0f);
    long long b = b0 + gm;
    out[b] = sg;
    out[(long long)B + b] = la;
  }
  #undef XW
}

extern "C" void kernel_launch(void* const* d_in, const int* in_sizes, int n_in,
                              void* d_out, int out_size, void* d_ws, size_t ws_size,
                              hipStream_t stream) {
  const float* occ  = (const float*)d_in[0];
  const float* Wg   = (const float*)d_in[1];
  const float* bias = (const float*)d_in[2];
  float* out = (float*)d_out;
  const int B = in_sizes[0] / NE;          // 262144
  unsigned short* wh = (unsigned short*)d_ws;
  unsigned short* wm = wh + NE * RR;
  unsigned short* wl = wm + NE * RR;       // 196608 B total in d_ws

  hipLaunchKernelGGL(wsplit3_kernel, dim3(NE * RR / 256), dim3(256), 0, stream,
                     Wg, wh, wm, wl);
  hipLaunchKernelGGL(jastrow_mfma, dim3(B / MT), dim3(256), 0, stream,
                     occ, wh, wm, wl, bias, out, B);
}